// Round 6
// baseline (145.271 us; speedup 1.0000x reference)
//
#include <hip/hip_runtime.h>
#include <math.h>

#define CC 256
#define NTOK 4096
#define NHEADS 8
#define HD 32
#define FFD 1024
#define LN_EPS 1e-5f
#define QSCALE 0.17677669529663687f  // 1/sqrt(32)

typedef __bf16 bf16x8 __attribute__((ext_vector_type(8)));
typedef float f32x4 __attribute__((ext_vector_type(4)));
typedef unsigned short u16x8 __attribute__((ext_vector_type(8)));

__device__ __forceinline__ unsigned short f2bf(float f) {
    unsigned u = __builtin_bit_cast(unsigned, f);
    u += 0x7fff + ((u >> 16) & 1);   // RNE
    return (unsigned short)(u >> 16);
}
__device__ __forceinline__ float bf2f(unsigned short h) {
    unsigned u = ((unsigned)h) << 16;
    return __builtin_bit_cast(float, u);
}
__device__ __forceinline__ void gload16(const unsigned short* g, unsigned short* l) {
    __builtin_amdgcn_global_load_lds(
        (const __attribute__((address_space(1))) unsigned int*)(const void*)g,
        (__attribute__((address_space(3))) unsigned int*)(void*)l, 16, 0, 0);
}

// ---------------- LayerNorm: one wave per token, fp32 in -> bf16 out -------
__device__ __forceinline__ void ln_row(const float* __restrict__ x, const float* __restrict__ g,
                                       const float* __restrict__ b, unsigned short* __restrict__ out,
                                       int tok, int lane) {
    const float4 v = ((const float4*)(x + (size_t)tok * CC))[lane];
    float s  = v.x + v.y + v.z + v.w;
    float ss = v.x * v.x + v.y * v.y + v.z * v.z + v.w * v.w;
    #pragma unroll
    for (int o = 32; o > 0; o >>= 1) { s += __shfl_xor(s, o); ss += __shfl_xor(ss, o); }
    float m   = s * (1.0f / CC);
    float var = ss * (1.0f / CC) - m * m;
    float r   = rsqrtf(var + LN_EPS);
    float4 gv = ((const float4*)g)[lane];
    float4 bv = ((const float4*)b)[lane];
    ushort4 o4;
    o4.x = f2bf((v.x - m) * r * gv.x + bv.x);
    o4.y = f2bf((v.y - m) * r * gv.y + bv.y);
    o4.z = f2bf((v.z - m) * r * gv.z + bv.z);
    o4.w = f2bf((v.w - m) * r * gv.w + bv.w);
    ((ushort4*)(out + (size_t)tok * CC))[lane] = o4;
}

__global__ void ln_kernel(const float* __restrict__ x, const float* __restrict__ g,
                          const float* __restrict__ b, unsigned short* __restrict__ out) {
    ln_row(x, g, b, out, blockIdx.x * 4 + (threadIdx.x >> 6), threadIdx.x & 63);
}

// ---------------- Merged setup: weight->fragment-major bf16, bias, LN1 -----
// Fragment-major B: frag chunk (nc, kc) holds 64 lanes x 8 bf16 at
// u16 offset ((nc*KC + kc)*64 + lane)*8, where lane=(sq<<4)|fr covers
// col n = nc*16+fr, k = kc*32 + sq*8 + e.  blocks 0..191: weight tiles;
// block 192: bias fuse; blocks 193..1216: LN1 rows.
__global__ void setup_kernel(const float* __restrict__ wq, const float* __restrict__ wk,
                             const float* __restrict__ wv, const float* __restrict__ wo,
                             const float* __restrict__ w1, const float* __restrict__ w2,
                             const float* __restrict__ bq, const float* __restrict__ bk,
                             const float* __restrict__ bv,
                             const float* __restrict__ x, const float* __restrict__ ln1_g,
                             const float* __restrict__ ln1_b,
                             unsigned short* __restrict__ wt_qkv, unsigned short* __restrict__ wo_t,
                             unsigned short* __restrict__ w1_t, unsigned short* __restrict__ w2_t,
                             float* __restrict__ bqkv, unsigned short* __restrict__ hs_bf) {
    int id = blockIdx.x;
    int t = threadIdx.x;
    if (id >= 193) {
        ln_row(x, ln1_g, ln1_b, hs_bf, (id - 193) * 4 + (t >> 6), t & 63);
        return;
    }
    if (id == 192) {
        bqkv[t]       = bq[t] * QSCALE;
        bqkv[256 + t] = bk[t];
        bqkv[512 + t] = bv[t];
        return;
    }
    const float* src; unsigned short* dst;
    int N, rowoff16 = 0, bx, by, KC = 8; float scale = 1.0f;
    if (id < 16)       { src = wq; dst = wt_qkv; N = 256;                  int l = id;       bx = l & 3;  by = l >> 2; scale = QSCALE; }
    else if (id < 32)  { src = wk; dst = wt_qkv; N = 256;  rowoff16 = 16;  int l = id - 16;  bx = l & 3;  by = l >> 2; }
    else if (id < 48)  { src = wv; dst = wt_qkv; N = 256;  rowoff16 = 32;  int l = id - 32;  bx = l & 3;  by = l >> 2; }
    else if (id < 64)  { src = wo; dst = wo_t;   N = 256;                  int l = id - 48;  bx = l & 3;  by = l >> 2; }
    else if (id < 128) { src = w1; dst = w1_t;   N = 1024;                 int l = id - 64;  bx = l & 15; by = l >> 4; }
    else               { src = w2; dst = w2_t;   N = 256;  KC = 32;        int l = id - 128; bx = l & 3;  by = l >> 2; }
    int n0 = bx * 64, k0 = by * 64;
    __shared__ float tile[64][65];
    int cc = t & 63, rb = t >> 6;
    #pragma unroll
    for (int i = 0; i < 16; i++) {
        int r = rb + i * 4;
        tile[r][cc] = src[(size_t)(k0 + r) * N + n0 + cc];   // tile[k][n]
    }
    __syncthreads();
    int lane = t & 63, fr = lane & 15, sq = lane >> 4, ncl = t >> 6;
    #pragma unroll
    for (int kcl = 0; kcl < 2; kcl++) {
        unsigned short tmp[8];
        #pragma unroll
        for (int e = 0; e < 8; e++)
            tmp[e] = f2bf(tile[kcl * 32 + sq * 8 + e][ncl * 16 + fr] * scale);
        int nc = rowoff16 + (n0 >> 4) + ncl;
        int kc = (k0 >> 5) + kcl;
        *(u16x8*)(dst + ((size_t)(nc * KC + kc) * 64 + lane) * 8) = *(const u16x8*)tmp;
    }
}

// ---------------- bf16 MFMA GEMM v3: A via LDS (2-phase dbuf), B direct ----
// A [M,KD] bf16 row-major; Bf fragment-major (see setup). 4 waves as
// WARPS_M x (4/WARPS_M); wave tile (BM/WARPS_M) x (BN/WARPS_N).
// B frags global-prefetched one K-step ahead (L2-resident weights).
template<int BM, int BN, int WARPS_M, int KD, int ACT, bool ADD_RES, bool OUT_BF16>
__global__ __launch_bounds__(256) void gemm_v3(
    const unsigned short* __restrict__ A, const unsigned short* __restrict__ Bf,
    const float* __restrict__ bias, const float* __restrict__ res,
    void* __restrict__ Cm, int N) {
    constexpr int WARPS_N = 4 / WARPS_M;
    constexpr int WM = BM / WARPS_M, WN = BN / WARPS_N;
    constexpr int MF = WM / 16, NF = WN / 16;
    constexpr int NIT = KD / 64;
    constexpr int KC = KD / 32;
    __shared__ unsigned short lds[2][BM * 64];
    const int t = threadIdx.x;
    const int lane = t & 63, w = t >> 6;
    const int wr = w / WARPS_N, wc = w % WARPS_N;
    const int bm = blockIdx.y * BM, bn = blockIdx.x * BN;
    const int fr = lane & 15, sq = lane >> 4;
    const int ncb = (bn >> 4) + wc * NF;

    auto stage = [&](int it, int buf) {
        unsigned short* La = lds[buf];
        #pragma unroll
        for (int i = 0; i < BM / 32; i++) {        // 2 slabs x BM x 4 chunks
            int c = t + i * 256;
            int s32 = c / (BM * 4), r = (c % (BM * 4)) >> 2, jj = c & 3;
            gload16(A + (size_t)(bm + r) * KD + it * 64 + s32 * 32 + jj * 8, La + c * 8);
        }
    };
    auto loadB = [&](bf16x8* bfrag, int s) {
        #pragma unroll
        for (int j = 0; j < NF; j++)
            bfrag[j] = *(const bf16x8*)(Bf + ((size_t)((ncb + j) * KC + s) * 64 + lane) * 8);
    };

    f32x4 acc[MF][NF] = {};
    bf16x8 bnext[NF];
    stage(0, 0);
    loadB(bnext, 0);
    for (int it = 0; it < NIT; ++it) {
        const int buf = it & 1;
        __syncthreads();                    // drains stage(it) (+ B prefetch)
        if (it + 1 < NIT) stage(it + 1, buf ^ 1);
        #pragma unroll
        for (int kk = 0; kk < 2; kk++) {
            bf16x8 bcur[NF];
            #pragma unroll
            for (int j = 0; j < NF; j++) bcur[j] = bnext[j];
            int s = it * 2 + kk + 1;
            if (s < 2 * NIT) loadB(bnext, s);
            const char* La = (const char*)(lds[buf]) + kk * BM * 64;
            bf16x8 af[MF];
            #pragma unroll
            for (int i = 0; i < MF; i++)
                af[i] = *(const bf16x8*)(La + (wr * WM + i * 16 + fr) * 64 + sq * 16);
            #pragma unroll
            for (int i = 0; i < MF; i++)
                #pragma unroll
                for (int j = 0; j < NF; j++)
                    acc[i][j] = __builtin_amdgcn_mfma_f32_16x16x32_bf16(af[i], bcur[j], acc[i][j], 0, 0, 0);
        }
    }
    // epilogue: C/D layout col=lane&15, row=(lane>>4)*4+reg
    #pragma unroll
    for (int i = 0; i < MF; i++) {
        int row0 = bm + wr * WM + i * 16 + sq * 4;
        #pragma unroll
        for (int j = 0; j < NF; j++) {
            int col = bn + wc * WN + j * 16 + fr;
            float bvv = bias[col];
            #pragma unroll
            for (int r = 0; r < 4; r++) {
                float v = acc[i][j][r] + bvv;
                if constexpr (ACT == 1) v = 0.5f * v * (1.0f + erff(v * 0.70710678118654752f));
                if constexpr (ADD_RES) v += res[(size_t)(row0 + r) * N + col];
                if constexpr (OUT_BF16)
                    ((unsigned short*)Cm)[(size_t)(row0 + r) * N + col] = f2bf(v);
                else
                    ((float*)Cm)[(size_t)(row0 + r) * N + col] = v;
            }
        }
    }
}

// ---------------- MFMA neighborhood attention (unchanged from R5) ----------
__global__ __launch_bounds__(256) void attn_mfma(
    const unsigned short* __restrict__ qkv, const float* __restrict__ rpb,
    unsigned short* __restrict__ ctx) {
    __shared__ __align__(16) unsigned short VT[128][136];
    __shared__ __align__(16) unsigned short Pl[4][16][136];
    __shared__ unsigned short tbl[16][112];
    __shared__ float rpbl[4][172];

    const int t = threadIdx.x;
    const int lane = t & 63, w = t >> 6;
    const int fr = lane & 15, sq = lane >> 4;
    const int bid = blockIdx.x;
    const int p = bid & 3, tile = (bid >> 2) & 63, hb = bid >> 8;
    const int ri = p >> 1, rj = p & 1;
    const int tgi = (tile >> 3) * 4, tgj = (tile & 7) * 4;
    const int kgi0 = min(max(tgi - 3, 0), 22);
    const int kgj0 = min(max(tgj - 3, 0), 22);
    const int head = hb * 4 + w;

    for (int i = lane; i < 169; i += 64)
        rpbl[w][i] = rpb[head * 169 + i];
    if (lane == 0) rpbl[w][169] = -1e30f;

    for (int e = t; e < 16 * 112; e += 256) {
        int q = e / 112, kk = e % 112;
        unsigned short idx = 169;
        if (kk < 100) {
            int kr = kk / 10, kc = kk % 10;
            int qgi = tgi + (q >> 2), qgj = tgj + (q & 3);
            int kgi = kgi0 + kr, kgj = kgj0 + kc;
            int si = min(max(qgi - 3, 0), 25), sj = min(max(qgj - 3, 0), 25);
            if (kgi >= si && kgi <= si + 6 && kgj >= sj && kgj <= sj + 6)
                idx = (unsigned short)((kgi - qgi + 6) * 13 + (kgj - qgj + 6));
        }
        tbl[q][kk] = idx;
    }

    for (int c0 = t; c0 < 1600; c0 += 256) {
        int key = c0 >> 4, ch8 = c0 & 15;
        int kr = key / 10, kc = key % 10;
        int kt = ((kgi0 + kr) * 2 + ri) * 64 + (kgj0 + kc) * 2 + rj;
        u16x8 vv = *(const u16x8*)(qkv + (size_t)kt * 768 + 512 + hb * 128 + ch8 * 8);
        #pragma unroll
        for (int e = 0; e < 8; e++) VT[ch8 * 8 + e][key] = vv[e];
    }
    for (int c0 = t; c0 < 128 * 14; c0 += 256) {
        int row = c0 / 14, cp = c0 % 14;
        *(unsigned*)&VT[row][100 + cp * 2] = 0;
    }
    __syncthreads();

    const int qtok = ((tgi + (fr >> 2)) * 2 + ri) * 64 + (tgj + (fr & 3)) * 2 + rj;
    bf16x8 qf = *(const bf16x8*)(qkv + (size_t)qtok * 768 + head * 32 + sq * 8);

    f32x4 sc[7];
    #pragma unroll
    for (int c = 0; c < 7; c++) {
        int kk = c * 16 + fr;
        if (kk > 99) kk = 99;
        int kr = kk / 10, kc = kk % 10;
        int kt = ((kgi0 + kr) * 2 + ri) * 64 + (kgj0 + kc) * 2 + rj;
        bf16x8 kf = *(const bf16x8*)(qkv + (size_t)kt * 768 + 256 + head * 32 + sq * 8);
        f32x4 z = {0.0f, 0.0f, 0.0f, 0.0f};
        sc[c] = __builtin_amdgcn_mfma_f32_16x16x32_bf16(kf, qf, z, 0, 0, 0);
    }
    #pragma unroll
    for (int c = 0; c < 7; c++)
        #pragma unroll
        for (int r = 0; r < 4; r++) {
            int idx = tbl[fr][c * 16 + 4 * sq + r];
            sc[c][r] += rpbl[w][idx];
        }

    float mx = -1e30f;
    #pragma unroll
    for (int c = 0; c < 7; c++)
        #pragma unroll
        for (int r = 0; r < 4; r++) mx = fmaxf(mx, sc[c][r]);
    mx = fmaxf(mx, __shfl_xor(mx, 16));
    mx = fmaxf(mx, __shfl_xor(mx, 32));
    float sum = 0.0f;
    #pragma unroll
    for (int c = 0; c < 7; c++)
        #pragma unroll
        for (int r = 0; r < 4; r++) {
            sc[c][r] = __expf(sc[c][r] - mx);
            sum += sc[c][r];
        }
    sum += __shfl_xor(sum, 16);
    sum += __shfl_xor(sum, 32);
    float inv = 1.0f / sum;

    #pragma unroll
    for (int c = 0; c < 7; c++)
        #pragma unroll
        for (int r = 0; r < 4; r++)
            Pl[w][fr][c * 16 + 4 * sq + r] = f2bf(sc[c][r] * inv);
    *(unsigned long long*)&Pl[w][fr][112 + sq * 4] = 0ull;

    f32x4 o0 = {0, 0, 0, 0}, o1 = {0, 0, 0, 0};
    #pragma unroll
    for (int m = 0; m < 4; m++) {
        bf16x8 pf = *(const bf16x8*)(&Pl[w][fr][m * 32 + sq * 8]);
        bf16x8 v0 = *(const bf16x8*)(&VT[w * 32 + fr][m * 32 + sq * 8]);
        bf16x8 v1 = *(const bf16x8*)(&VT[w * 32 + 16 + fr][m * 32 + sq * 8]);
        o0 = __builtin_amdgcn_mfma_f32_16x16x32_bf16(pf, v0, o0, 0, 0, 0);
        o1 = __builtin_amdgcn_mfma_f32_16x16x32_bf16(pf, v1, o1, 0, 0, 0);
    }
    #pragma unroll
    for (int r = 0; r < 4; r++) {
        int tok = ((tgi + sq) * 2 + ri) * 64 + (tgj + r) * 2 + rj;
        ctx[(size_t)tok * 256 + head * 32 + fr]      = f2bf(o0[r]);
        ctx[(size_t)tok * 256 + head * 32 + 16 + fr] = f2bf(o1[r]);
    }
}

extern "C" void kernel_launch(void* const* d_in, const int* in_sizes, int n_in,
                              void* d_out, int out_size, void* d_ws, size_t ws_size,
                              hipStream_t stream) {
    const float* x     = (const float*)d_in[0];
    const float* ln1_g = (const float*)d_in[1];
    const float* ln1_b = (const float*)d_in[2];
    const float* wq    = (const float*)d_in[3];
    const float* bq    = (const float*)d_in[4];
    const float* wk    = (const float*)d_in[5];
    const float* bk    = (const float*)d_in[6];
    const float* wv    = (const float*)d_in[7];
    const float* bv    = (const float*)d_in[8];
    const float* rpb   = (const float*)d_in[9];
    const float* wo    = (const float*)d_in[10];
    const float* bo    = (const float*)d_in[11];
    const float* ln2_g = (const float*)d_in[12];
    const float* ln2_b = (const float*)d_in[13];
    const float* w1    = (const float*)d_in[14];
    const float* b1    = (const float*)d_in[15];
    const float* w2    = (const float*)d_in[16];
    const float* b2    = (const float*)d_in[17];

    char* wsb = (char*)d_ws;
    unsigned short* hs_bf  = (unsigned short*)(wsb);                    // 2 MB
    unsigned short* qkv_bf = (unsigned short*)(wsb + (2u << 20));       // 6 MB
    unsigned short* ctx_bf = (unsigned short*)(wsb + (8u << 20));       // 2 MB
    float*          hs2    = (float*)(wsb + (10u << 20));               // 4 MB
    unsigned short* y1_bf  = (unsigned short*)(wsb + (14u << 20));      // 2 MB
    unsigned short* gm_bf  = (unsigned short*)(wsb + (16u << 20));      // 8 MB
    unsigned short* wt_qkv = (unsigned short*)(wsb + (24u << 20));      // 768x256
    unsigned short* wo_t   = wt_qkv + 768 * 256;                        // 256x256
    unsigned short* w1_t   = wo_t + 256 * 256;                          // 1024x256
    unsigned short* w2_t   = w1_t + 1024 * 256;                         // 256x1024
    float*          bqkv   = (float*)(w2_t + 256 * 1024);               // 768

    // 0. merged: weight frag-convert + bias fuse + LN1
    setup_kernel<<<1217, 256, 0, stream>>>(wq, wk, wv, wo, w1, w2, bq, bk, bv,
                                           x, ln1_g, ln1_b,
                                           wt_qkv, wo_t, w1_t, w2_t, bqkv, hs_bf);
    // 1. fused QKV: [4096,768] = hs @ [wq|wk|wv]
    gemm_v3<128, 64, 4, 256, 0, false, true><<<dim3(12, 32), 256, 0, stream>>>(
        hs_bf, wt_qkv, bqkv, nullptr, qkv_bf, 768);
    // 2. neighborhood attention (MFMA, parity-lattice tiles)
    attn_mfma<<<512, 256, 0, stream>>>(qkv_bf, rpb, ctx_bf);
    // 3. hs2 = x + ctx@wo + bo  (fp32)
    gemm_v3<64, 64, 2, 256, 0, true, false><<<dim3(4, 64), 256, 0, stream>>>(
        ctx_bf, wo_t, bo, x, hs2, 256);
    // 4. y1 = LN2(hs2)
    ln_kernel<<<NTOK / 4, 256, 0, stream>>>(hs2, ln2_g, ln2_b, y1_bf);
    // 5. gmid = gelu(y1@w1 + b1)
    gemm_v3<128, 64, 4, 256, 1, false, true><<<dim3(16, 32), 256, 0, stream>>>(
        y1_bf, w1_t, b1, nullptr, gm_bf, 1024);
    // 6. out = hs2 + gmid@w2 + b2  (fp32)
    gemm_v3<64, 64, 2, 1024, 0, true, false><<<dim3(4, 64), 256, 0, stream>>>(
        gm_bf, w2_t, b2, hs2, (float*)d_out, 256);
}

// Round 7
// 142.746 us; speedup vs baseline: 1.0177x; 1.0177x over previous
//
#include <hip/hip_runtime.h>
#include <math.h>

#define CC 256
#define NTOK 4096
#define NHEADS 8
#define HD 32
#define FFD 1024
#define LN_EPS 1e-5f
#define QSCALE 0.17677669529663687f  // 1/sqrt(32)

typedef __bf16 bf16x8 __attribute__((ext_vector_type(8)));
typedef float f32x4 __attribute__((ext_vector_type(4)));
typedef unsigned short u16x8 __attribute__((ext_vector_type(8)));

__device__ __forceinline__ unsigned short f2bf(float f) {
    unsigned u = __builtin_bit_cast(unsigned, f);
    u += 0x7fff + ((u >> 16) & 1);   // RNE
    return (unsigned short)(u >> 16);
}
__device__ __forceinline__ float bf2f(unsigned short h) {
    unsigned u = ((unsigned)h) << 16;
    return __builtin_bit_cast(float, u);
}
__device__ __forceinline__ void gload16(const unsigned short* g, unsigned short* l) {
    __builtin_amdgcn_global_load_lds(
        (const __attribute__((address_space(1))) unsigned int*)(const void*)g,
        (__attribute__((address_space(3))) unsigned int*)(void*)l, 16, 0, 0);
}

// ---------------- LayerNorm: one wave per token, fp32 in -> bf16 out -------
__device__ __forceinline__ void ln_row(const float* __restrict__ x, const float* __restrict__ g,
                                       const float* __restrict__ b, unsigned short* __restrict__ out,
                                       int tok, int lane) {
    const float4 v = ((const float4*)(x + (size_t)tok * CC))[lane];
    float s  = v.x + v.y + v.z + v.w;
    float ss = v.x * v.x + v.y * v.y + v.z * v.z + v.w * v.w;
    #pragma unroll
    for (int o = 32; o > 0; o >>= 1) { s += __shfl_xor(s, o); ss += __shfl_xor(ss, o); }
    float m   = s * (1.0f / CC);
    float var = ss * (1.0f / CC) - m * m;
    float r   = rsqrtf(var + LN_EPS);
    float4 gv = ((const float4*)g)[lane];
    float4 bv = ((const float4*)b)[lane];
    ushort4 o4;
    o4.x = f2bf((v.x - m) * r * gv.x + bv.x);
    o4.y = f2bf((v.y - m) * r * gv.y + bv.y);
    o4.z = f2bf((v.z - m) * r * gv.z + bv.z);
    o4.w = f2bf((v.w - m) * r * gv.w + bv.w);
    ((ushort4*)(out + (size_t)tok * CC))[lane] = o4;
}

__global__ void ln_kernel(const float* __restrict__ x, const float* __restrict__ g,
                          const float* __restrict__ b, unsigned short* __restrict__ out) {
    ln_row(x, g, b, out, blockIdx.x * 4 + (threadIdx.x >> 6), threadIdx.x & 63);
}

// ---------------- Merged setup: weight->fragment-major bf16, bias, LN1 -----
// Fragment-major: chunk (nc, kc) holds 64 lanes x 8 bf16 at u16 offset
// ((nc*KC + kc)*64 + lane)*8; lane=(sq<<4)|fr -> col nc*16+fr, k kc*32+sq*8+e.
__global__ void setup_kernel(const float* __restrict__ wq, const float* __restrict__ wk,
                             const float* __restrict__ wv, const float* __restrict__ wo,
                             const float* __restrict__ w1, const float* __restrict__ w2,
                             const float* __restrict__ bq, const float* __restrict__ bk,
                             const float* __restrict__ bv,
                             const float* __restrict__ x, const float* __restrict__ ln1_g,
                             const float* __restrict__ ln1_b,
                             unsigned short* __restrict__ wt_qkv, unsigned short* __restrict__ wo_t,
                             unsigned short* __restrict__ w1_t, unsigned short* __restrict__ w2_t,
                             float* __restrict__ bqkv, unsigned short* __restrict__ hs_bf) {
    int id = blockIdx.x;
    int t = threadIdx.x;
    if (id >= 193) {
        ln_row(x, ln1_g, ln1_b, hs_bf, (id - 193) * 4 + (t >> 6), t & 63);
        return;
    }
    if (id == 192) {
        bqkv[t]       = bq[t] * QSCALE;
        bqkv[256 + t] = bk[t];
        bqkv[512 + t] = bv[t];
        return;
    }
    const float* src; unsigned short* dst;
    int N, rowoff16 = 0, bx, by, KC = 8; float scale = 1.0f;
    if (id < 16)       { src = wq; dst = wt_qkv; N = 256;                  int l = id;       bx = l & 3;  by = l >> 2; scale = QSCALE; }
    else if (id < 32)  { src = wk; dst = wt_qkv; N = 256;  rowoff16 = 16;  int l = id - 16;  bx = l & 3;  by = l >> 2; }
    else if (id < 48)  { src = wv; dst = wt_qkv; N = 256;  rowoff16 = 32;  int l = id - 32;  bx = l & 3;  by = l >> 2; }
    else if (id < 64)  { src = wo; dst = wo_t;   N = 256;                  int l = id - 48;  bx = l & 3;  by = l >> 2; }
    else if (id < 128) { src = w1; dst = w1_t;   N = 1024;                 int l = id - 64;  bx = l & 15; by = l >> 4; }
    else               { src = w2; dst = w2_t;   N = 256;  KC = 32;        int l = id - 128; bx = l & 3;  by = l >> 2; }
    int n0 = bx * 64, k0 = by * 64;
    __shared__ float tile[64][65];
    int cc = t & 63, rb = t >> 6;
    #pragma unroll
    for (int i = 0; i < 16; i++) {
        int r = rb + i * 4;
        tile[r][cc] = src[(size_t)(k0 + r) * N + n0 + cc];   // tile[k][n]
    }
    __syncthreads();
    int lane = t & 63, fr = lane & 15, sq = lane >> 4, ncl = t >> 6;
    #pragma unroll
    for (int kcl = 0; kcl < 2; kcl++) {
        unsigned short tmp[8];
        #pragma unroll
        for (int e = 0; e < 8; e++)
            tmp[e] = f2bf(tile[kcl * 32 + sq * 8 + e][ncl * 16 + fr] * scale);
        int nc = rowoff16 + (n0 >> 4) + ncl;
        int kc = (k0 >> 5) + kcl;
        *(u16x8*)(dst + ((size_t)(nc * KC + kc) * 64 + lane) * 8) = *(const u16x8*)tmp;
    }
}

// ------ bf16 MFMA GEMM, full-chunk-resident fragment-major, one barrier ----
// A [M,KD] bf16 row-major (gathered to fragment-major LDS via per-lane
// global_load_lds sources); Bf fragment-major global (setup layout).
// Per 256-K chunk: stage A+B -> ONE __syncthreads -> 8 straight-line K-steps
// of contiguous (conflict-free) ds_read_b128 + MFMA. XCD-swizzled blocks.
template<int BM, int BN, int WARPS_M, int KD, int ACT, bool ADD_RES, bool OUT_BF16>
__global__ __launch_bounds__(256) void gemm_fr(
    const unsigned short* __restrict__ A, const unsigned short* __restrict__ Bf,
    const float* __restrict__ bias, const float* __restrict__ res,
    void* __restrict__ Cm, int N) {
    constexpr int WARPS_N = 4 / WARPS_M;
    constexpr int WM = BM / WARPS_M, WN = BN / WARPS_N;
    constexpr int MF = WM / 16, NF = WN / 16;
    constexpr int CHUNK = 256;
    constexpr int NCH = KD / CHUNK;
    constexpr int SC = CHUNK / 32;            // k-steps per chunk
    constexpr int KC = KD / 32;               // global B k-chunk count
    constexpr int ACH = (BM / 16) * SC;       // A 1KB-chunks per stage
    constexpr int BCH = (BN / 16) * SC;
    __shared__ unsigned short lds[(BM + BN) * CHUNK];
    unsigned short* La = lds;
    unsigned short* Lb = lds + BM * CHUNK;
    const int t = threadIdx.x, lane = t & 63, w = t >> 6;
    const int wr = w / WARPS_N, wc = w % WARPS_N;
    const int fr = lane & 15, sq = lane >> 4;
    // bijective XCD-chunk swizzle (all grids are multiples of 8)
    const int gx = gridDim.x;
    const int nwg = gx * gridDim.y;
    const int l0 = blockIdx.y * gx + blockIdx.x;
    const int nl = (l0 & 7) * (nwg >> 3) + (l0 >> 3);
    const int bm = (nl / gx) * BM, bn = (nl % gx) * BN;

    f32x4 acc[MF][NF] = {};
    for (int ch = 0; ch < NCH; ++ch) {
        #pragma unroll
        for (int i = 0; i < ACH / 4; i++) {            // A gather -> frag-major LDS
            int c = i * 4 + w, mc = c / SC, s = c % SC;
            gload16(A + (size_t)(bm + mc * 16 + fr) * KD + ch * CHUNK + s * 32 + sq * 8,
                    La + c * 512 + lane * 8);
        }
        #pragma unroll
        for (int i = 0; i < BCH / 4; i++) {            // B frag-major copy
            int c = i * 4 + w, ncl = c / SC, s = c % SC;
            gload16(Bf + ((size_t)(((bn >> 4) + ncl) * KC + ch * SC + s) * 64 + lane) * 8,
                    Lb + c * 512 + lane * 8);
        }
        __syncthreads();                               // single drain per chunk
        #pragma unroll
        for (int s = 0; s < SC; s++) {
            bf16x8 af[MF], bfr[NF];
            #pragma unroll
            for (int i = 0; i < MF; i++)
                af[i] = *(const bf16x8*)(La + ((wr * MF + i) * SC + s) * 512 + lane * 8);
            #pragma unroll
            for (int j = 0; j < NF; j++)
                bfr[j] = *(const bf16x8*)(Lb + ((wc * NF + j) * SC + s) * 512 + lane * 8);
            #pragma unroll
            for (int i = 0; i < MF; i++)
                #pragma unroll
                for (int j = 0; j < NF; j++)
                    acc[i][j] = __builtin_amdgcn_mfma_f32_16x16x32_bf16(af[i], bfr[j], acc[i][j], 0, 0, 0);
        }
        if (ch + 1 < NCH) __syncthreads();
    }
    // epilogue: C/D layout col=lane&15, row=(lane>>4)*4+reg
    #pragma unroll
    for (int i = 0; i < MF; i++) {
        int row0 = bm + wr * WM + i * 16 + sq * 4;
        #pragma unroll
        for (int j = 0; j < NF; j++) {
            int col = bn + wc * WN + j * 16 + fr;
            float bvv = bias[col];
            #pragma unroll
            for (int r = 0; r < 4; r++) {
                float v = acc[i][j][r] + bvv;
                if constexpr (ACT == 1) v = 0.5f * v * (1.0f + erff(v * 0.70710678118654752f));
                if constexpr (ADD_RES) v += res[(size_t)(row0 + r) * N + col];
                if constexpr (OUT_BF16)
                    ((unsigned short*)Cm)[(size_t)(row0 + r) * N + col] = f2bf(v);
                else
                    ((float*)Cm)[(size_t)(row0 + r) * N + col] = v;
            }
        }
    }
}

// ---------------- MFMA neighborhood attention (proven, unchanged) ----------
__global__ __launch_bounds__(256) void attn_mfma(
    const unsigned short* __restrict__ qkv, const float* __restrict__ rpb,
    unsigned short* __restrict__ ctx) {
    __shared__ __align__(16) unsigned short VT[128][136];
    __shared__ __align__(16) unsigned short Pl[4][16][136];
    __shared__ unsigned short tbl[16][112];
    __shared__ float rpbl[4][172];

    const int t = threadIdx.x;
    const int lane = t & 63, w = t >> 6;
    const int fr = lane & 15, sq = lane >> 4;
    const int bid = blockIdx.x;
    const int p = bid & 3, tile = (bid >> 2) & 63, hb = bid >> 8;
    const int ri = p >> 1, rj = p & 1;
    const int tgi = (tile >> 3) * 4, tgj = (tile & 7) * 4;
    const int kgi0 = min(max(tgi - 3, 0), 22);
    const int kgj0 = min(max(tgj - 3, 0), 22);
    const int head = hb * 4 + w;

    for (int i = lane; i < 169; i += 64)
        rpbl[w][i] = rpb[head * 169 + i];
    if (lane == 0) rpbl[w][169] = -1e30f;

    for (int e = t; e < 16 * 112; e += 256) {
        int q = e / 112, kk = e % 112;
        unsigned short idx = 169;
        if (kk < 100) {
            int kr = kk / 10, kc = kk % 10;
            int qgi = tgi + (q >> 2), qgj = tgj + (q & 3);
            int kgi = kgi0 + kr, kgj = kgj0 + kc;
            int si = min(max(qgi - 3, 0), 25), sj = min(max(qgj - 3, 0), 25);
            if (kgi >= si && kgi <= si + 6 && kgj >= sj && kgj <= sj + 6)
                idx = (unsigned short)((kgi - qgi + 6) * 13 + (kgj - qgj + 6));
        }
        tbl[q][kk] = idx;
    }

    for (int c0 = t; c0 < 1600; c0 += 256) {
        int key = c0 >> 4, ch8 = c0 & 15;
        int kr = key / 10, kc = key % 10;
        int kt = ((kgi0 + kr) * 2 + ri) * 64 + (kgj0 + kc) * 2 + rj;
        u16x8 vv = *(const u16x8*)(qkv + (size_t)kt * 768 + 512 + hb * 128 + ch8 * 8);
        #pragma unroll
        for (int e = 0; e < 8; e++) VT[ch8 * 8 + e][key] = vv[e];
    }
    for (int c0 = t; c0 < 128 * 14; c0 += 256) {
        int row = c0 / 14, cp = c0 % 14;
        *(unsigned*)&VT[row][100 + cp * 2] = 0;
    }
    __syncthreads();

    const int qtok = ((tgi + (fr >> 2)) * 2 + ri) * 64 + (tgj + (fr & 3)) * 2 + rj;
    bf16x8 qf = *(const bf16x8*)(qkv + (size_t)qtok * 768 + head * 32 + sq * 8);

    f32x4 sc[7];
    #pragma unroll
    for (int c = 0; c < 7; c++) {
        int kk = c * 16 + fr;
        if (kk > 99) kk = 99;
        int kr = kk / 10, kc = kk % 10;
        int kt = ((kgi0 + kr) * 2 + ri) * 64 + (kgj0 + kc) * 2 + rj;
        bf16x8 kf = *(const bf16x8*)(qkv + (size_t)kt * 768 + 256 + head * 32 + sq * 8);
        f32x4 z = {0.0f, 0.0f, 0.0f, 0.0f};
        sc[c] = __builtin_amdgcn_mfma_f32_16x16x32_bf16(kf, qf, z, 0, 0, 0);
    }
    #pragma unroll
    for (int c = 0; c < 7; c++)
        #pragma unroll
        for (int r = 0; r < 4; r++) {
            int idx = tbl[fr][c * 16 + 4 * sq + r];
            sc[c][r] += rpbl[w][idx];
        }

    float mx = -1e30f;
    #pragma unroll
    for (int c = 0; c < 7; c++)
        #pragma unroll
        for (int r = 0; r < 4; r++) mx = fmaxf(mx, sc[c][r]);
    mx = fmaxf(mx, __shfl_xor(mx, 16));
    mx = fmaxf(mx, __shfl_xor(mx, 32));
    float sum = 0.0f;
    #pragma unroll
    for (int c = 0; c < 7; c++)
        #pragma unroll
        for (int r = 0; r < 4; r++) {
            sc[c][r] = __expf(sc[c][r] - mx);
            sum += sc[c][r];
        }
    sum += __shfl_xor(sum, 16);
    sum += __shfl_xor(sum, 32);
    float inv = 1.0f / sum;

    #pragma unroll
    for (int c = 0; c < 7; c++)
        #pragma unroll
        for (int r = 0; r < 4; r++)
            Pl[w][fr][c * 16 + 4 * sq + r] = f2bf(sc[c][r] * inv);
    *(unsigned long long*)&Pl[w][fr][112 + sq * 4] = 0ull;

    f32x4 o0 = {0, 0, 0, 0}, o1 = {0, 0, 0, 0};
    #pragma unroll
    for (int m = 0; m < 4; m++) {
        bf16x8 pf = *(const bf16x8*)(&Pl[w][fr][m * 32 + sq * 8]);
        bf16x8 v0 = *(const bf16x8*)(&VT[w * 32 + fr][m * 32 + sq * 8]);
        bf16x8 v1 = *(const bf16x8*)(&VT[w * 32 + 16 + fr][m * 32 + sq * 8]);
        o0 = __builtin_amdgcn_mfma_f32_16x16x32_bf16(pf, v0, o0, 0, 0, 0);
        o1 = __builtin_amdgcn_mfma_f32_16x16x32_bf16(pf, v1, o1, 0, 0, 0);
    }
    #pragma unroll
    for (int r = 0; r < 4; r++) {
        int tok = ((tgi + sq) * 2 + ri) * 64 + (tgj + r) * 2 + rj;
        ctx[(size_t)tok * 256 + head * 32 + fr]      = f2bf(o0[r]);
        ctx[(size_t)tok * 256 + head * 32 + 16 + fr] = f2bf(o1[r]);
    }
}

extern "C" void kernel_launch(void* const* d_in, const int* in_sizes, int n_in,
                              void* d_out, int out_size, void* d_ws, size_t ws_size,
                              hipStream_t stream) {
    const float* x     = (const float*)d_in[0];
    const float* ln1_g = (const float*)d_in[1];
    const float* ln1_b = (const float*)d_in[2];
    const float* wq    = (const float*)d_in[3];
    const float* bq    = (const float*)d_in[4];
    const float* wk    = (const float*)d_in[5];
    const float* bk    = (const float*)d_in[6];
    const float* wv    = (const float*)d_in[7];
    const float* bv    = (const float*)d_in[8];
    const float* rpb   = (const float*)d_in[9];
    const float* wo    = (const float*)d_in[10];
    const float* bo    = (const float*)d_in[11];
    const float* ln2_g = (const float*)d_in[12];
    const float* ln2_b = (const float*)d_in[13];
    const float* w1    = (const float*)d_in[14];
    const float* b1    = (const float*)d_in[15];
    const float* w2    = (const float*)d_in[16];
    const float* b2    = (const float*)d_in[17];

    char* wsb = (char*)d_ws;
    unsigned short* hs_bf  = (unsigned short*)(wsb);                    // 2 MB
    unsigned short* qkv_bf = (unsigned short*)(wsb + (2u << 20));       // 6 MB
    unsigned short* ctx_bf = (unsigned short*)(wsb + (8u << 20));       // 2 MB
    float*          hs2    = (float*)(wsb + (10u << 20));               // 4 MB
    unsigned short* y1_bf  = (unsigned short*)(wsb + (14u << 20));      // 2 MB
    unsigned short* gm_bf  = (unsigned short*)(wsb + (16u << 20));      // 8 MB
    unsigned short* wt_qkv = (unsigned short*)(wsb + (24u << 20));      // 768x256
    unsigned short* wo_t   = wt_qkv + 768 * 256;                        // 256x256
    unsigned short* w1_t   = wo_t + 256 * 256;                          // 1024x256
    unsigned short* w2_t   = w1_t + 1024 * 256;                         // 256x1024
    float*          bqkv   = (float*)(w2_t + 256 * 1024);               // 768

    // 0. merged: weight frag-convert + bias fuse + LN1
    setup_kernel<<<1217, 256, 0, stream>>>(wq, wk, wv, wo, w1, w2, bq, bk, bv,
                                           x, ln1_g, ln1_b,
                                           wt_qkv, wo_t, w1_t, w2_t, bqkv, hs_bf);
    // 1. fused QKV: [4096,768] = hs @ [wq|wk|wv]
    gemm_fr<64, 64, 2, 256, 0, false, true><<<dim3(12, 64), 256, 0, stream>>>(
        hs_bf, wt_qkv, bqkv, nullptr, qkv_bf, 768);
    // 2. neighborhood attention (MFMA, parity-lattice tiles)
    attn_mfma<<<512, 256, 0, stream>>>(qkv_bf, rpb, ctx_bf);
    // 3. hs2 = x + ctx@wo + bo  (fp32)
    gemm_fr<64, 64, 2, 256, 0, true, false><<<dim3(4, 64), 256, 0, stream>>>(
        ctx_bf, wo_t, bo, x, hs2, 256);
    // 4. y1 = LN2(hs2)
    ln_kernel<<<NTOK / 4, 256, 0, stream>>>(hs2, ln2_g, ln2_b, y1_bf);
    // 5. gmid = gelu(y1@w1 + b1)
    gemm_fr<64, 64, 2, 256, 1, false, true><<<dim3(16, 64), 256, 0, stream>>>(
        y1_bf, w1_t, b1, nullptr, gm_bf, 1024);
    // 6. out = hs2 + gmid@w2 + b2  (fp32)
    gemm_fr<32, 64, 1, 1024, 0, true, false><<<dim3(4, 128), 256, 0, stream>>>(
        gm_bf, w2_t, b2, hs2, (float*)d_out, 256);
}

// Round 10
// 133.829 us; speedup vs baseline: 1.0855x; 1.0666x over previous
//
#include <hip/hip_runtime.h>
#include <math.h>

#define CC 256
#define NTOK 4096
#define NHEADS 8
#define HD 32
#define FFD 1024
#define LN_EPS 1e-5f
#define QSCALE 0.17677669529663687f  // 1/sqrt(32)

typedef __bf16 bf16x8 __attribute__((ext_vector_type(8)));
typedef float f32x4 __attribute__((ext_vector_type(4)));
typedef unsigned short u16x8 __attribute__((ext_vector_type(8)));

__device__ __forceinline__ unsigned short f2bf(float f) {
    unsigned u = __builtin_bit_cast(unsigned, f);
    u += 0x7fff + ((u >> 16) & 1);   // RNE
    return (unsigned short)(u >> 16);
}
__device__ __forceinline__ float bf2f(unsigned short h) {
    unsigned u = ((unsigned)h) << 16;
    return __builtin_bit_cast(float, u);
}
__device__ __forceinline__ void gload16(const unsigned short* g, unsigned short* l) {
    __builtin_amdgcn_global_load_lds(
        (const __attribute__((address_space(1))) unsigned int*)(const void*)g,
        (__attribute__((address_space(3))) unsigned int*)(void*)l, 16, 0, 0);
}

// ---------------- LayerNorm: one wave per token, fp32 in -> bf16 out -------
__device__ __forceinline__ void ln_row(const float* __restrict__ x, const float* __restrict__ g,
                                       const float* __restrict__ b, unsigned short* __restrict__ out,
                                       int tok, int lane) {
    const float4 v = ((const float4*)(x + (size_t)tok * CC))[lane];
    float s  = v.x + v.y + v.z + v.w;
    float ss = v.x * v.x + v.y * v.y + v.z * v.z + v.w * v.w;
    #pragma unroll
    for (int o = 32; o > 0; o >>= 1) { s += __shfl_xor(s, o); ss += __shfl_xor(ss, o); }
    float m   = s * (1.0f / CC);
    float var = ss * (1.0f / CC) - m * m;
    float r   = rsqrtf(var + LN_EPS);
    float4 gv = ((const float4*)g)[lane];
    float4 bv = ((const float4*)b)[lane];
    ushort4 o4;
    o4.x = f2bf((v.x - m) * r * gv.x + bv.x);
    o4.y = f2bf((v.y - m) * r * gv.y + bv.y);
    o4.z = f2bf((v.z - m) * r * gv.z + bv.z);
    o4.w = f2bf((v.w - m) * r * gv.w + bv.w);
    ((ushort4*)(out + (size_t)tok * CC))[lane] = o4;
}

__global__ void ln_kernel(const float* __restrict__ x, const float* __restrict__ g,
                          const float* __restrict__ b, unsigned short* __restrict__ out) {
    ln_row(x, g, b, out, blockIdx.x * 4 + (threadIdx.x >> 6), threadIdx.x & 63);
}

// ---------------- Merged setup: W^T bf16 (row-major [N][K]) + bias + LN1 ---
// blocks 0..191: 64x64 transpose tiles; 192: bias fuse; 193..1216: LN1.
__global__ void setup_kernel(const float* __restrict__ wq, const float* __restrict__ wk,
                             const float* __restrict__ wv, const float* __restrict__ wo,
                             const float* __restrict__ w1, const float* __restrict__ w2,
                             const float* __restrict__ bq, const float* __restrict__ bk,
                             const float* __restrict__ bv,
                             const float* __restrict__ x, const float* __restrict__ ln1_g,
                             const float* __restrict__ ln1_b,
                             unsigned short* __restrict__ wt_qkv, unsigned short* __restrict__ wo_t,
                             unsigned short* __restrict__ w1_t, unsigned short* __restrict__ w2_t,
                             float* __restrict__ bqkv, unsigned short* __restrict__ hs_bf) {
    int id = blockIdx.x;
    int t = threadIdx.x;
    if (id >= 193) {
        ln_row(x, ln1_g, ln1_b, hs_bf, (id - 193) * 4 + (t >> 6), t & 63);
        return;
    }
    if (id == 192) {
        bqkv[t]       = bq[t] * QSCALE;
        bqkv[256 + t] = bk[t];
        bqkv[512 + t] = bv[t];
        return;
    }
    const float* src; unsigned short* dst;
    int Kd, N, rowoff = 0, bx, by; float scale = 1.0f;
    if (id < 16)       { src = wq; dst = wt_qkv; Kd = 256;  N = 256;  scale = QSCALE; int l = id;       bx = l & 3;  by = l >> 2; }
    else if (id < 32)  { src = wk; dst = wt_qkv; Kd = 256;  N = 256;  rowoff = 256;   int l = id - 16;  bx = l & 3;  by = l >> 2; }
    else if (id < 48)  { src = wv; dst = wt_qkv; Kd = 256;  N = 256;  rowoff = 512;   int l = id - 32;  bx = l & 3;  by = l >> 2; }
    else if (id < 64)  { src = wo; dst = wo_t;   Kd = 256;  N = 256;                  int l = id - 48;  bx = l & 3;  by = l >> 2; }
    else if (id < 128) { src = w1; dst = w1_t;   Kd = 256;  N = 1024;                 int l = id - 64;  bx = l & 15; by = l >> 4; }
    else               { src = w2; dst = w2_t;   Kd = 1024; N = 256;                  int l = id - 128; bx = l & 3;  by = l >> 2; }
    int n0 = bx * 64, k0 = by * 64;
    __shared__ float tile[64][65];
    int cc = t & 63, rb = t >> 6;
    #pragma unroll
    for (int i = 0; i < 16; i++) {
        int r = rb + i * 4;
        tile[r][cc] = src[(size_t)(k0 + r) * N + n0 + cc];   // tile[k][n]
    }
    __syncthreads();
    int n = t >> 2;
    #pragma unroll
    for (int i = 0; i < 8; i++) {
        int p = (t & 3) + i * 4;
        unsigned lo = f2bf(tile[2 * p][n] * scale);
        unsigned hi = f2bf(tile[2 * p + 1][n] * scale);
        *(unsigned*)(dst + (size_t)(rowoff + n0 + n) * Kd + k0 + 2 * p) = lo | (hi << 16);
    }
}

// -------- bf16 MFMA GEMM, 3-buffer counted-vmcnt pipeline (T4-light) -------
// A [M,KD] bf16, Bt [N,KD] bf16 (W^T row-major). BK=64, 4 waves (2x2).
// Per iter: s_waitcnt vmcnt(L) [stage(it) landed, stage(it+1) stays in
// flight] -> s_barrier [compute(it-1) closed by all waves] -> issue
// stage(it+2) [overwrites buf freed by compute(it-1)] -> compute(it).
// Never vmcnt(0) until the last iteration.
template<int BM, int BN, int KD, int ACT, bool ADD_RES, bool OUT_BF16>
__global__ __launch_bounds__(256) void gemm_tb(
    const unsigned short* __restrict__ A, const unsigned short* __restrict__ Bt,
    const float* __restrict__ bias, const float* __restrict__ res,
    void* __restrict__ Cm, int N) {
    constexpr int WM = BM / 2, WN = BN / 2;
    constexpr int MF = WM / 16, NF = WN / 16;
    constexpr int NIT = KD / 64;
    constexpr int LA = BM * 8 / 256;     // per-thread A gload16 per stage
    constexpr int LB = BN * 8 / 256;
    constexpr int L  = LA + LB;          // per-thread loads per stage
    __shared__ unsigned short lds[3][(BM + BN) * 64];
    const int t = threadIdx.x;
    const int lane = t & 63, w = t >> 6;
    const int wr = w >> 1, wc = w & 1;
    const int bm = blockIdx.y * BM, bn = blockIdx.x * BN;
    const int fr = lane & 15, sq = lane >> 4;

    auto stage = [&](int it, int buf) {
        unsigned short* La = lds[buf];
        unsigned short* Lb = lds[buf] + BM * 64;
        #pragma unroll
        for (int i = 0; i < LA; i++) {
            int c = t + i * 256;
            int kk = c / (BM * 4), r = (c % (BM * 4)) >> 2, jj = c & 3;
            gload16(A + (size_t)(bm + r) * KD + it * 64 + kk * 32 + jj * 8, La + c * 8);
        }
        #pragma unroll
        for (int i = 0; i < LB; i++) {
            int c = t + i * 256;
            int kk = c / (BN * 4), r = (c % (BN * 4)) >> 2, jj = c & 3;
            gload16(Bt + (size_t)(bn + r) * KD + it * 64 + kk * 32 + jj * 8, Lb + c * 8);
        }
    };

    f32x4 acc[MF][NF] = {};
    stage(0, 0);
    stage(1, 1);
    #pragma unroll
    for (int it = 0; it < NIT; ++it) {
        if (it < NIT - 1) {
            if constexpr (L == 4) asm volatile("s_waitcnt vmcnt(4)" ::: "memory");
            else if constexpr (L == 3) asm volatile("s_waitcnt vmcnt(3)" ::: "memory");
            else asm volatile("s_waitcnt vmcnt(2)" ::: "memory");
        } else {
            asm volatile("s_waitcnt vmcnt(0)" ::: "memory");
        }
        __builtin_amdgcn_s_barrier();
        if (it + 2 < NIT) stage(it + 2, (it + 2) % 3);
        const int buf = it % 3;
        #pragma unroll
        for (int kk = 0; kk < 2; kk++) {
            const char* La = (const char*)(lds[buf]) + kk * BM * 64;
            const char* Lb = (const char*)(lds[buf] + BM * 64) + kk * BN * 64;
            bf16x8 af[MF], bfr[NF];
            #pragma unroll
            for (int i = 0; i < MF; i++)
                af[i] = *(const bf16x8*)(La + (wr * WM + i * 16 + fr) * 64 + sq * 16);
            #pragma unroll
            for (int j = 0; j < NF; j++)
                bfr[j] = *(const bf16x8*)(Lb + (wc * WN + j * 16 + fr) * 64 + sq * 16);
            #pragma unroll
            for (int i = 0; i < MF; i++)
                #pragma unroll
                for (int j = 0; j < NF; j++)
                    acc[i][j] = __builtin_amdgcn_mfma_f32_16x16x32_bf16(af[i], bfr[j], acc[i][j], 0, 0, 0);
        }
    }
    // epilogue: C/D layout col=lane&15, row=(lane>>4)*4+reg
    #pragma unroll
    for (int i = 0; i < MF; i++) {
        int row0 = bm + wr * WM + i * 16 + sq * 4;
        #pragma unroll
        for (int j = 0; j < NF; j++) {
            int col = bn + wc * WN + j * 16 + fr;
            float bvv = bias[col];
            #pragma unroll
            for (int r = 0; r < 4; r++) {
                float v = acc[i][j][r] + bvv;
                if constexpr (ACT == 1) v = 0.5f * v * (1.0f + erff(v * 0.70710678118654752f));
                if constexpr (ADD_RES) v += res[(size_t)(row0 + r) * N + col];
                if constexpr (OUT_BF16)
                    ((unsigned short*)Cm)[(size_t)(row0 + r) * N + col] = f2bf(v);
                else
                    ((float*)Cm)[(size_t)(row0 + r) * N + col] = v;
            }
        }
    }
}

// ---------------- MFMA neighborhood attention (proven; + setprio) ----------
__global__ __launch_bounds__(256) void attn_mfma(
    const unsigned short* __restrict__ qkv, const float* __restrict__ rpb,
    unsigned short* __restrict__ ctx) {
    __shared__ __align__(16) unsigned short VT[128][136];
    __shared__ __align__(16) unsigned short Pl[4][16][136];
    __shared__ unsigned short tbl[16][112];
    __shared__ float rpbl[4][172];

    const int t = threadIdx.x;
    const int lane = t & 63, w = t >> 6;
    const int fr = lane & 15, sq = lane >> 4;
    const int bid = blockIdx.x;
    const int p = bid & 3, tile = (bid >> 2) & 63, hb = bid >> 8;
    const int ri = p >> 1, rj = p & 1;
    const int tgi = (tile >> 3) * 4, tgj = (tile & 7) * 4;
    const int kgi0 = min(max(tgi - 3, 0), 22);
    const int kgj0 = min(max(tgj - 3, 0), 22);
    const int head = hb * 4 + w;

    for (int i = lane; i < 169; i += 64)
        rpbl[w][i] = rpb[head * 169 + i];
    if (lane == 0) rpbl[w][169] = -1e30f;

    for (int e = t; e < 16 * 112; e += 256) {
        int q = e / 112, kk = e % 112;
        unsigned short idx = 169;
        if (kk < 100) {
            int kr = kk / 10, kc = kk % 10;
            int qgi = tgi + (q >> 2), qgj = tgj + (q & 3);
            int kgi = kgi0 + kr, kgj = kgj0 + kc;
            int si = min(max(qgi - 3, 0), 25), sj = min(max(qgj - 3, 0), 25);
            if (kgi >= si && kgi <= si + 6 && kgj >= sj && kgj <= sj + 6)
                idx = (unsigned short)((kgi - qgi + 6) * 13 + (kgj - qgj + 6));
        }
        tbl[q][kk] = idx;
    }

    for (int c0 = t; c0 < 1600; c0 += 256) {
        int key = c0 >> 4, ch8 = c0 & 15;
        int kr = key / 10, kc = key % 10;
        int kt = ((kgi0 + kr) * 2 + ri) * 64 + (kgj0 + kc) * 2 + rj;
        u16x8 vv = *(const u16x8*)(qkv + (size_t)kt * 768 + 512 + hb * 128 + ch8 * 8);
        #pragma unroll
        for (int e = 0; e < 8; e++) VT[ch8 * 8 + e][key] = vv[e];
    }
    for (int c0 = t; c0 < 128 * 14; c0 += 256) {
        int row = c0 / 14, cp = c0 % 14;
        *(unsigned*)&VT[row][100 + cp * 2] = 0;
    }
    __syncthreads();

    const int qtok = ((tgi + (fr >> 2)) * 2 + ri) * 64 + (tgj + (fr & 3)) * 2 + rj;
    bf16x8 qf = *(const bf16x8*)(qkv + (size_t)qtok * 768 + head * 32 + sq * 8);

    f32x4 sc[7];
    __builtin_amdgcn_s_setprio(1);
    #pragma unroll
    for (int c = 0; c < 7; c++) {
        int kk = c * 16 + fr;
        if (kk > 99) kk = 99;
        int kr = kk / 10, kc = kk % 10;
        int kt = ((kgi0 + kr) * 2 + ri) * 64 + (kgj0 + kc) * 2 + rj;
        bf16x8 kf = *(const bf16x8*)(qkv + (size_t)kt * 768 + 256 + head * 32 + sq * 8);
        f32x4 z = {0.0f, 0.0f, 0.0f, 0.0f};
        sc[c] = __builtin_amdgcn_mfma_f32_16x16x32_bf16(kf, qf, z, 0, 0, 0);
    }
    __builtin_amdgcn_s_setprio(0);
    #pragma unroll
    for (int c = 0; c < 7; c++)
        #pragma unroll
        for (int r = 0; r < 4; r++) {
            int idx = tbl[fr][c * 16 + 4 * sq + r];
            sc[c][r] += rpbl[w][idx];
        }

    float mx = -1e30f;
    #pragma unroll
    for (int c = 0; c < 7; c++)
        #pragma unroll
        for (int r = 0; r < 4; r++) mx = fmaxf(mx, sc[c][r]);
    mx = fmaxf(mx, __shfl_xor(mx, 16));
    mx = fmaxf(mx, __shfl_xor(mx, 32));
    float sum = 0.0f;
    #pragma unroll
    for (int c = 0; c < 7; c++)
        #pragma unroll
        for (int r = 0; r < 4; r++) {
            sc[c][r] = __expf(sc[c][r] - mx);
            sum += sc[c][r];
        }
    sum += __shfl_xor(sum, 16);
    sum += __shfl_xor(sum, 32);
    float inv = 1.0f / sum;

    #pragma unroll
    for (int c = 0; c < 7; c++)
        #pragma unroll
        for (int r = 0; r < 4; r++)
            Pl[w][fr][c * 16 + 4 * sq + r] = f2bf(sc[c][r] * inv);
    *(unsigned long long*)&Pl[w][fr][112 + sq * 4] = 0ull;

    f32x4 o0 = {0, 0, 0, 0}, o1 = {0, 0, 0, 0};
    __builtin_amdgcn_s_setprio(1);
    #pragma unroll
    for (int m = 0; m < 4; m++) {
        bf16x8 pf = *(const bf16x8*)(&Pl[w][fr][m * 32 + sq * 8]);
        bf16x8 v0 = *(const bf16x8*)(&VT[w * 32 + fr][m * 32 + sq * 8]);
        bf16x8 v1 = *(const bf16x8*)(&VT[w * 32 + 16 + fr][m * 32 + sq * 8]);
        o0 = __builtin_amdgcn_mfma_f32_16x16x32_bf16(pf, v0, o0, 0, 0, 0);
        o1 = __builtin_amdgcn_mfma_f32_16x16x32_bf16(pf, v1, o1, 0, 0, 0);
    }
    __builtin_amdgcn_s_setprio(0);
    #pragma unroll
    for (int r = 0; r < 4; r++) {
        int tok = ((tgi + sq) * 2 + ri) * 64 + (tgj + r) * 2 + rj;
        ctx[(size_t)tok * 256 + head * 32 + fr]      = f2bf(o0[r]);
        ctx[(size_t)tok * 256 + head * 32 + 16 + fr] = f2bf(o1[r]);
    }
}

extern "C" void kernel_launch(void* const* d_in, const int* in_sizes, int n_in,
                              void* d_out, int out_size, void* d_ws, size_t ws_size,
                              hipStream_t stream) {
    const float* x     = (const float*)d_in[0];
    const float* ln1_g = (const float*)d_in[1];
    const float* ln1_b = (const float*)d_in[2];
    const float* wq    = (const float*)d_in[3];
    const float* bq    = (const float*)d_in[4];
    const float* wk    = (const float*)d_in[5];
    const float* bk    = (const float*)d_in[6];
    const float* wv    = (const float*)d_in[7];
    const float* bv    = (const float*)d_in[8];
    const float* rpb   = (const float*)d_in[9];
    const float* wo    = (const float*)d_in[10];
    const float* bo    = (const float*)d_in[11];
    const float* ln2_g = (const float*)d_in[12];
    const float* ln2_b = (const float*)d_in[13];
    const float* w1    = (const float*)d_in[14];
    const float* b1    = (const float*)d_in[15];
    const float* w2    = (const float*)d_in[16];
    const float* b2    = (const float*)d_in[17];

    char* wsb = (char*)d_ws;
    unsigned short* hs_bf  = (unsigned short*)(wsb);                    // 2 MB
    unsigned short* qkv_bf = (unsigned short*)(wsb + (2u << 20));       // 6 MB
    unsigned short* ctx_bf = (unsigned short*)(wsb + (8u << 20));       // 2 MB
    float*          hs2    = (float*)(wsb + (10u << 20));               // 4 MB
    unsigned short* y1_bf  = (unsigned short*)(wsb + (14u << 20));      // 2 MB
    unsigned short* gm_bf  = (unsigned short*)(wsb + (16u << 20));      // 8 MB
    unsigned short* wt_qkv = (unsigned short*)(wsb + (24u << 20));      // 768x256
    unsigned short* wo_t   = wt_qkv + 768 * 256;                        // 256x256
    unsigned short* w1_t   = wo_t + 256 * 256;                          // 1024x256
    unsigned short* w2_t   = w1_t + 1024 * 256;                         // 256x1024
    float*          bqkv   = (float*)(w2_t + 256 * 1024);               // 768

    // 0. merged: weight transpose/convert + bias fuse + LN1
    setup_kernel<<<1217, 256, 0, stream>>>(wq, wk, wv, wo, w1, w2, bq, bk, bv,
                                           x, ln1_g, ln1_b,
                                           wt_qkv, wo_t, w1_t, w2_t, bqkv, hs_bf);
    // 1. fused QKV: [4096,768] = hs @ [wq|wk|wv]
    gemm_tb<64, 64, 256, 0, false, true><<<dim3(12, 64), 256, 0, stream>>>(
        hs_bf, wt_qkv, bqkv, nullptr, qkv_bf, 768);
    // 2. neighborhood attention (MFMA, parity-lattice tiles)
    attn_mfma<<<512, 256, 0, stream>>>(qkv_bf, rpb, ctx_bf);
    // 3. hs2 = x + ctx@wo + bo  (fp32)
    gemm_tb<32, 64, 256, 0, true, false><<<dim3(4, 128), 256, 0, stream>>>(
        ctx_bf, wo_t, bo, x, hs2, 256);
    // 4. y1 = LN2(hs2)
    ln_kernel<<<NTOK / 4, 256, 0, stream>>>(hs2, ln2_g, ln2_b, y1_bf);
    // 5. gmid = gelu(y1@w1 + b1)
    gemm_tb<64, 64, 256, 1, false, true><<<dim3(16, 64), 256, 0, stream>>>(
        y1_bf, w1_t, b1, nullptr, gm_bf, 1024);
    // 6. out = hs2 + gmid@w2 + b2  (fp32)
    gemm_tb<32, 64, 1024, 0, true, false><<<dim3(4, 128), 256, 0, stream>>>(
        gm_bf, w2_t, b2, hs2, (float*)d_out, 256);
}